// Round 18
// baseline (104.885 us; speedup 1.0000x reference)
//
#include <hip/hip_runtime.h>
#include <hip/hip_bf16.h>
#include <math.h>

#define NH 8
#define HS 32
#define SD 257
#define SS 256
#define NN 2048
#define BB 4
#define INV_CURV 10.0f
#define RCONST 3.16227766016837933f
#define SCALE 0.17677669529663687f
#define M0NEG 1.76776695296636881f   // -score_upper_bound = (1/CURV)*SCALE
#define LOG2E 1.44269504088896341f
#define SCL2  (SCALE * LOG2E)
#define M02   (M0NEG * LOG2E)
#define EPSF 1e-9f

typedef unsigned short ushortT;
typedef unsigned int uintT;
typedef __attribute__((ext_vector_type(8))) short bf16x8;
typedef __attribute__((ext_vector_type(8))) _Float16 f16x8;
typedef __attribute__((ext_vector_type(2))) __fp16 fp16x2_builtin;
typedef __attribute__((ext_vector_type(4))) float f32x4;
typedef __attribute__((ext_vector_type(16))) float f32x16;

union U4  { uint4 u; bf16x8 h; };
union U4f { uint4 u; f16x8 h; };

__device__ inline ushortT f2bf(float f) {
    __hip_bfloat16 h = __float2bfloat16(f);
    return *(ushortT*)&h;
}
__device__ inline uintT packbf(float a, float b) {
    return (uintT)f2bf(a) | ((uintT)f2bf(b) << 16);
}
__device__ inline float bfround(float f) {           // round-to-bf16, widen
    return __bfloat162float(__float2bfloat16(f));
}
__device__ inline uintT pkrtz(float a, float b) {    // v_cvt_pkrtz_f16_f32
    union { fp16x2_builtin h; uintT u; } z;
    z.h = __builtin_amdgcn_cvt_pkrtz(a, b);
    return z.u;
}
__device__ inline ushortT f2h(float f) {
    _Float16 h = (_Float16)f;
    return *(ushortT*)&h;
}
// vdst.hi31 <-> vsrc.lo31 quadrant exchange (gfx950). Non-volatile: pure
// function of inputs -> compiler may schedule/pipeline freely across it.
__device__ inline void permswap(uintT &a, uintT &b) {
    asm("v_permlane32_swap_b32 %0, %1" : "+v"(a), "+v"(b));
}

// ---------------------------------------------------------------------------
// Prep: xbf[n][256] = bf16(x[n][1..256]) (blocks 0..1023).
// Blocks 1024..1055: LDS-tiled COALESCED transposes (verified round 16).
// ---------------------------------------------------------------------------
__global__ __launch_bounds__(256) void prep_kernel(
    const float* __restrict__ x,
    const float* __restrict__ Wq, const float* __restrict__ Wk,
    const float* __restrict__ Wv, const float* __restrict__ Wo,
    ushortT* __restrict__ xbf, ushortT* __restrict__ WT,
    ushortT* __restrict__ WoT)
{
    __shared__ float tile[256][33];
    const int b = blockIdx.x, tid = threadIdx.x;
    if (b < 1024) {
        const int tok = b * 8 + (tid >> 5);
        const int c   = (tid & 31) * 8;
        const float* src = x + (size_t)tok * SD + 1 + c;
        uint4 w4;
        w4.x = packbf(src[0], src[1]);
        w4.y = packbf(src[2], src[3]);
        w4.z = packbf(src[4], src[5]);
        w4.w = packbf(src[6], src[7]);
        *(uint4*)(xbf + (size_t)tok * 256 + c) = w4;
        return;
    }
    const int idx = b - 1024;          // 0..31
    const int cc  = tid & 31;          // column within panel
    const int rr  = tid >> 5;          // row sub-index (0..7)

    if (idx < 24) {
        const int m = idx >> 3, h = idx & 7;
        const float* src = (m == 0 ? Wq : (m == 1 ? Wk : Wv)) + (size_t)h * SD * HS;
        #pragma unroll
        for (int i = 0; i < 32; ++i) {
            const int d = 1 + i * 8 + rr;
            tile[d - 1][cc] = src[(size_t)d * HS + cc];
        }
        __syncthreads();
        const int s = cc, dk0 = rr * 32;
        ushortT* dst = WT + ((size_t)idx * 32 + s) * 256 + dk0;
        #pragma unroll
        for (int j = 0; j < 32; j += 8) {
            uint4 w4;
            w4.x = packbf(tile[dk0 + j + 0][s], tile[dk0 + j + 1][s]);
            w4.y = packbf(tile[dk0 + j + 2][s], tile[dk0 + j + 3][s]);
            w4.z = packbf(tile[dk0 + j + 4][s], tile[dk0 + j + 5][s]);
            w4.w = packbf(tile[dk0 + j + 6][s], tile[dk0 + j + 7][s]);
            *(uint4*)(dst + j) = w4;
        }
    } else {
        const int jc = idx - 24;       // Wo column chunk: cols 32*jc..32*jc+31
        #pragma unroll
        for (int i = 0; i < 32; ++i) {
            const int d = 1 + i * 8 + rr;
            tile[d - 1][cc] = Wo[(size_t)d * SS + 32 * jc + cc];
        }
        __syncthreads();
        const int s = cc, dk0 = rr * 32;
        ushortT* dst = WoT + ((size_t)jc * 32 + s) * 256 + dk0;
        #pragma unroll
        for (int j = 0; j < 32; j += 8) {
            uint4 w4;
            w4.x = packbf(tile[dk0 + j + 0][s], tile[dk0 + j + 1][s]);
            w4.y = packbf(tile[dk0 + j + 2][s], tile[dk0 + j + 3][s]);
            w4.z = packbf(tile[dk0 + j + 4][s], tile[dk0 + j + 5][s]);
            w4.w = packbf(tile[dk0 + j + 6][s], tile[dk0 + j + 7][s]);
            *(uint4*)(dst + j) = w4;
        }
    }
}

// ---------------------------------------------------------------------------
// Proj via MFMA (verified round 10 inner code). ONE MAT PER WAVE:
// grid = 512 token-tiles x 6 mat-groups; block (tile, mg), wave w does
// mat mt = mg*4+w. 12288 waves -> ~12 waves/SIMD (was 4).
// qx row (stride 48): [qs*SCL2 (32) | -u,-u,-du,1 | 0 x12]
// kx row (stride 48): [ks (32)      |  v,dv,v,M02 | 0 x12]
// vtT stored fp16 transposed [bh][d][n].
// ---------------------------------------------------------------------------
__global__ __launch_bounds__(256) void proj_mfma(
    const float* __restrict__ x, const ushortT* __restrict__ xbf,
    const ushortT* __restrict__ WT,
    const float* __restrict__ Wq, const float* __restrict__ Wk,
    const float* __restrict__ Wv,
    const float* __restrict__ bq, const float* __restrict__ bk,
    const float* __restrict__ bv,
    ushortT* __restrict__ qx, ushortT* __restrict__ kx,
    ushortT* __restrict__ vtT)
{
    const int tok0 = (blockIdx.x / 6) * 16;
    const int mg   = blockIdx.x % 6;
    const int w = threadIdx.x >> 6, lane = threadIdx.x & 63;
    const int g = lane >> 4, c = lane & 15;
    const int b = tok0 >> 11, n0 = tok0 & (NN - 1);

    U4 xf[8];
    const ushortT* xr = xbf + (size_t)(tok0 + c) * 256 + 8 * g;
    #pragma unroll
    for (int k = 0; k < 8; ++k) xf[k].u = *(const uint4*)(xr + 32 * k);
    const float xt1 = x[(size_t)(tok0 + c) * SD];

    {
        const int mt = mg * 4 + w;
        const int m = mt >> 3, h = mt & 7;
        const ushortT* Wb = WT + (size_t)mt * 32 * 256;
        const float* Wsrc = (m == 0 ? Wq : (m == 1 ? Wk : Wv)) + (size_t)h * SD * HS;
        const float* bsrc = (m == 0 ? bq : (m == 1 ? bk : bv)) + h * HS;

        f32x4 a0 = {0.f,0.f,0.f,0.f}, a1 = {0.f,0.f,0.f,0.f};
        #pragma unroll
        for (int k = 0; k < 8; ++k) {
            U4 A0, A1;
            A0.u = *(const uint4*)(Wb + (size_t)c * 256 + 32 * k + 8 * g);
            A1.u = *(const uint4*)(Wb + (size_t)(16 + c) * 256 + 32 * k + 8 * g);
            a0 = __builtin_amdgcn_mfma_f32_16x16x32_bf16(A0.h, xf[k].h, a0, 0, 0, 0);
            a1 = __builtin_amdgcn_mfma_f32_16x16x32_bf16(A1.h, xf[k].h, a1, 0, 0, 0);
        }
        float ns = 0.f;
        #pragma unroll
        for (int r = 0; r < 4; ++r) {
            a0[r] = fmaf(Wsrc[4 * g + r], xt1, a0[r]) + bsrc[4 * g + r];
            a1[r] = fmaf(Wsrc[16 + 4 * g + r], xt1, a1[r]) + bsrc[16 + 4 * g + r];
            ns += a0[r] * a0[r] + a1[r] * a1[r];
        }
        ns += __shfl_xor(ns, 16, 64);
        ns += __shfl_xor(ns, 32, 64);           // full |space|^2 of token c
        const float tcomp = sqrtf(INV_CURV + ns); // time component

        if (m < 2) {
            const size_t tb = (size_t)(b * NH + h) * NN + n0 + c;
            ushortT* dst = (m == 0 ? qx : kx) + tb * 48;
            uint2 u0, u1;
            if (m == 0) {
                u0.x = packbf(a0[0]*SCL2, a0[1]*SCL2); u0.y = packbf(a0[2]*SCL2, a0[3]*SCL2);
                u1.x = packbf(a1[0]*SCL2, a1[1]*SCL2); u1.y = packbf(a1[2]*SCL2, a1[3]*SCL2);
            } else {
                u0.x = packbf(a0[0], a0[1]); u0.y = packbf(a0[2], a0[3]);
                u1.x = packbf(a1[0], a1[1]); u1.y = packbf(a1[2], a1[3]);
            }
            *(uint2*)(dst + 4 * g) = u0;
            *(uint2*)(dst + 16 + 4 * g) = u1;
            if (g == 2) {
                uint4 e;
                if (m == 0) {
                    const float qtS = tcomp * SCL2;
                    const float uf  = bfround(qtS);
                    const float du  = qtS - uf;
                    e.x = packbf(-uf, -uf);
                    e.y = packbf(-du, 1.0f);
                } else {
                    const float vf = bfround(tcomp);
                    const float dv = tcomp - vf;
                    e.x = packbf(tcomp, dv);
                    e.y = packbf(tcomp, M02);
                }
                e.z = 0u; e.w = 0u;
                *(uint4*)(dst + 32) = e;
            }
            if (g == 3) {
                uint4 z; z.x = 0u; z.y = 0u; z.z = 0u; z.w = 0u;
                *(uint4*)(dst + 40) = z;
            }
        } else {
            const float xn  = sqrtf(fmaxf(ns, EPSF));
            const float z   = fmaxf(tcomp / RCONST, 1.0f + 1e-7f);
            const float dd  = RCONST * logf(z + sqrtf(z * z - 1.0f));
            const float fac = dd / xn;
            const size_t vb = (size_t)(b * NH + h) * HS;
            #pragma unroll
            for (int r = 0; r < 4; ++r) {
                vtT[(vb + 4 * g + r) * NN + n0 + c]      = f2h(fac * a0[r]);
                vtT[(vb + 16 + 4 * g + r) * NN + n0 + c] = f2h(fac * a1[r]);
            }
        }
    }
}

// ---------------------------------------------------------------------------
// Kernel 2: flash attention, in-block K-split x4 + XCD swizzle (verified
// round 13) + bf16 cat/hsq epilogue (verified round 15). Plain 256 bounds.
// ---------------------------------------------------------------------------
__global__ __launch_bounds__(256) void attn_mfma32s(
    const ushortT* __restrict__ qx, const ushortT* __restrict__ kx,
    const ushortT* __restrict__ vtT, ushortT* __restrict__ catbf,
    float* __restrict__ hsq)
{
    __shared__ float lacc[4][32][33];
    __shared__ float lsum[4][32];
    const int wk   = (blockIdx.x & 7) * 256 + (blockIdx.x >> 3);
    const int bh   = wk >> 6;
    const int qblk = wk & 63;
    const int wid  = threadIdx.x >> 6;
    const int lane = threadIdx.x & 63;
    const int h2 = lane >> 5;          // k-half selector
    const int cq = lane & 31;          // col index (q / key / d per fragment)
    const int qb = qblk * 32;

    const size_t bhNN = (size_t)bh * NN;
    U4 qf0, qf1, qf2;
    const ushortT* qrow = qx + (bhNN + qb + cq) * 48;
    qf0.u = *(const uint4*)(qrow + 8 * h2);
    qf1.u = *(const uint4*)(qrow + 16 + 8 * h2);
    qf2.u = *(const uint4*)(qrow + 32 + 8 * h2);

    f32x16 acc = {0.f,0.f,0.f,0.f,0.f,0.f,0.f,0.f,
                  0.f,0.f,0.f,0.f,0.f,0.f,0.f,0.f};
    float sum = 0.f;

    const ushortT* kp = kx  + bhNN * 48;
    const ushortT* vp = vtT + bhNN * HS;   // [32 d][NN], fp16

    const int tBeg = wid * 512;
    #pragma unroll 2
    for (int t = tBeg; t < tBeg + 512; t += 32) {
        const ushortT* krow = kp + (size_t)(t + cq) * 48;
        U4 k0, k1, k2;
        k0.u = *(const uint4*)(krow + 8 * h2);
        k1.u = *(const uint4*)(krow + 16 + 8 * h2);
        k2.u = *(const uint4*)(krow + 32 + 8 * h2);
        f32x16 sc = {0.f,0.f,0.f,0.f,0.f,0.f,0.f,0.f,
                     0.f,0.f,0.f,0.f,0.f,0.f,0.f,0.f};
        sc = __builtin_amdgcn_mfma_f32_32x32x16_bf16(k0.h, qf0.h, sc, 0, 0, 0);
        sc = __builtin_amdgcn_mfma_f32_32x32x16_bf16(k1.h, qf1.h, sc, 0, 0, 0);
        sc = __builtin_amdgcn_mfma_f32_32x32x16_bf16(k2.h, qf2.h, sc, 0, 0, 0);

        float p[16];
        #pragma unroll
        for (int r = 0; r < 16; ++r) {
            p[r] = __builtin_amdgcn_exp2f(sc[r]);
            sum += p[r];
        }
        uintT w0 = pkrtz(p[0],  p[1]),  w1 = pkrtz(p[2],  p[3]);
        uintT w2 = pkrtz(p[4],  p[5]),  w3 = pkrtz(p[6],  p[7]);
        uintT w4 = pkrtz(p[8],  p[9]),  w5 = pkrtz(p[10], p[11]);
        uintT w6 = pkrtz(p[12], p[13]), w7 = pkrtz(p[14], p[15]);
        permswap(w0, w2); permswap(w1, w3);   // keys 0-15 B-frag
        permswap(w4, w6); permswap(w5, w7);   // keys 16-31 B-frag
        U4f pa, pb;
        pa.u.x = w0; pa.u.y = w1; pa.u.z = w2; pa.u.w = w3;
        pb.u.x = w4; pb.u.y = w5; pb.u.z = w6; pb.u.w = w7;

        U4f v0, v1;
        v0.u = *(const uint4*)(vp + (size_t)cq * NN + t + 8 * h2);
        v1.u = *(const uint4*)(vp + (size_t)cq * NN + t + 16 + 8 * h2);
        acc = __builtin_amdgcn_mfma_f32_32x32x16_f16(v0.h, pa.h, acc, 0, 0, 0);
        acc = __builtin_amdgcn_mfma_f32_32x32x16_f16(v1.h, pb.h, acc, 0, 0, 0);
    }

    sum += __shfl_xor(sum, 32, 64);           // this wave's denominator, query cq
    if (lane < 32) lsum[wid][cq] = sum;
    #pragma unroll
    for (int r = 0; r < 16; ++r)
        lacc[wid][cq][(r & 3) + 8 * (r >> 2) + 4 * h2] = acc[r];
    __syncthreads();

    // Combine 4 key-splits; 8 threads per query, 4 dims each.
    const int qq = threadIdx.x >> 3;
    const int d0 = (threadIdx.x & 7) * 4;
    const float s   = lsum[0][qq] + lsum[1][qq] + lsum[2][qq] + lsum[3][qq];
    const float inv = 1.0f / s;
    float tv[4];
    float un2 = 0.f;
    #pragma unroll
    for (int i = 0; i < 4; ++i) {
        tv[i] = (lacc[0][qq][d0 + i] + lacc[1][qq][d0 + i]
               + lacc[2][qq][d0 + i] + lacc[3][qq][d0 + i]) * inv;
        un2 = fmaf(tv[i], tv[i], un2);
    }
    un2 += __shfl_xor(un2, 1, 64);
    un2 += __shfl_xor(un2, 2, 64);
    un2 += __shfl_xor(un2, 4, 64);            // full 32-dim sumsq of query qq
    const float un  = sqrtf(fmaxf(un2, 1e-18f));
    const float fac = RCONST * sinhf(un / RCONST) / un;

    const int b = bh >> 3, hH = bh & 7;
    const size_t tokIdx = (size_t)(b * NN + qb + qq);
    uint2 o2;
    o2.x = packbf(fac * tv[0], fac * tv[1]);
    o2.y = packbf(fac * tv[2], fac * tv[3]);
    *(uint2*)(catbf + tokIdx * SS + hH * HS + d0) = o2;
    if ((threadIdx.x & 7) == 0)
        hsq[tokIdx * NH + hH] = fac * fac * un2;   // |space_h|^2 of this head
}

// ---------------------------------------------------------------------------
// Kernel 3: output Lorentz FC via MFMA (verified round 15 form).
// ---------------------------------------------------------------------------
__global__ __launch_bounds__(256) void out_mfma(
    const ushortT* __restrict__ catbf, const ushortT* __restrict__ WoT,
    const float* __restrict__ Wo, const float* __restrict__ bo,
    const float* __restrict__ hsq, float* __restrict__ out)
{
    __shared__ float ylds[16][SS + 1];
    __shared__ float redt[16][4];
    const int tok0 = blockIdx.x * 16;
    const int w = threadIdx.x >> 6, lane = threadIdx.x & 63;
    const int g = lane >> 4, c = lane & 15;

    U4 bf[8];
    const ushortT* cr = catbf + (size_t)(tok0 + c) * SS + 8 * g;
    #pragma unroll
    for (int k = 0; k < 8; ++k) bf[k].u = *(const uint4*)(cr + 32 * k);

    const float4 h0 = *(const float4*)(hsq + (size_t)(tok0 + c) * NH);
    const float4 h1 = *(const float4*)(hsq + (size_t)(tok0 + c) * NH + 4);
    const float timec = sqrtf(INV_CURV + h0.x + h0.y + h0.z + h0.w
                                        + h1.x + h1.y + h1.z + h1.w);

    float ysq = 0.f;
    #pragma unroll
    for (int t4 = 0; t4 < 4; ++t4) {
        const int t = 4 * w + t4;
        f32x4 a = {0.f, 0.f, 0.f, 0.f};
        #pragma unroll
        for (int k = 0; k < 8; ++k) {
            U4 A;
            A.u = *(const uint4*)(WoT + (size_t)(16 * t + c) * 256 + 32 * k + 8 * g);
            a = __builtin_amdgcn_mfma_f32_16x16x32_bf16(A.h, bf[k].h, a, 0, 0, 0);
        }
        #pragma unroll
        for (int r = 0; r < 4; ++r) {
            const int s = 16 * t + 4 * g + r;
            const float y = a[r] + fmaf(Wo[s], timec, bo[s]);  // Wo row 0 = time row
            ylds[c][s] = y;
            ysq = fmaf(y, y, ysq);
        }
    }
    ysq += __shfl_xor(ysq, 16, 64);
    ysq += __shfl_xor(ysq, 32, 64);   // per (w,c): Sigma over this wave's 64 s
    if (lane < 16) redt[c][w] = ysq;
    __syncthreads();

    #pragma unroll
    for (int j = 0; j < 16; ++j)
        out[(size_t)(tok0 + j) * SD + 1 + threadIdx.x] = ylds[j][threadIdx.x];
    if (threadIdx.x < 16) {
        const int j = threadIdx.x;
        const float ys = redt[j][0] + redt[j][1] + redt[j][2] + redt[j][3];
        out[(size_t)(tok0 + j) * SD] = sqrtf(INV_CURV + ys);
    }
}

// ---------------------------------------------------------------------------
extern "C" void kernel_launch(void* const* d_in, const int* in_sizes, int n_in,
                              void* d_out, int out_size, void* d_ws, size_t ws_size,
                              hipStream_t stream)
{
    const float* x  = (const float*)d_in[0];
    const float* Wq = (const float*)d_in[1];
    const float* bq = (const float*)d_in[2];
    const float* Wk = (const float*)d_in[3];
    const float* bk = (const float*)d_in[4];
    const float* Wv = (const float*)d_in[5];
    const float* bv = (const float*)d_in[6];
    const float* Wo = (const float*)d_in[7];
    const float* bo = (const float*)d_in[8];
    float* out = (float*)d_out;

    char* w = (char*)d_ws;
    ushortT* xbf   = (ushortT*)(w);                         // 4 MB
    ushortT* qx    = (ushortT*)(w + (size_t)4194304);       // 6 MB (48-dim rows)
    ushortT* kx    = (ushortT*)(w + (size_t)10485760);      // 6 MB
    ushortT* vtT   = (ushortT*)(w + (size_t)16777216);      // 4 MB (fp16)
    ushortT* catbf = (ushortT*)(w + (size_t)20971520);      // 4 MB (bf16)
    ushortT* WT    = (ushortT*)(w + (size_t)25165824);      // 384 KB
    ushortT* WoT   = (ushortT*)(w + (size_t)25559040);      // 128 KB
    float*   hsq   = (float*)  (w + (size_t)25690112);      // 256 KB

    prep_kernel<<<1056, 256, 0, stream>>>(x, Wq, Wk, Wv, Wo, xbf, WT, WoT);
    proj_mfma<<<3072, 256, 0, stream>>>(x, xbf, WT, Wq, Wk, Wv,
                                        bq, bk, bv, qx, kx, vtT);
    attn_mfma32s<<<2048, 256, 0, stream>>>(qx, kx, vtT, catbf, hsq);
    out_mfma<<<BB * NN / 16, 256, 0, stream>>>(catbf, WoT, Wo, bo, hsq, out);
}

// Round 19
// 98.751 us; speedup vs baseline: 1.0621x; 1.0621x over previous
//
#include <hip/hip_runtime.h>
#include <hip/hip_bf16.h>
#include <math.h>

#define NH 8
#define HS 32
#define SD 257
#define SS 256
#define NN 2048
#define BB 4
#define INV_CURV 10.0f
#define RCONST 3.16227766016837933f
#define SCALE 0.17677669529663687f
#define M0NEG 1.76776695296636881f   // -score_upper_bound = (1/CURV)*SCALE
#define LOG2E 1.44269504088896341f
#define SCL2  (SCALE * LOG2E)
#define M02   (M0NEG * LOG2E)
#define EPSF 1e-9f

typedef unsigned short ushortT;
typedef unsigned int uintT;
typedef __attribute__((ext_vector_type(8))) short bf16x8;
typedef __attribute__((ext_vector_type(8))) _Float16 f16x8;
typedef __attribute__((ext_vector_type(2))) __fp16 fp16x2_builtin;
typedef __attribute__((ext_vector_type(4))) float f32x4;
typedef __attribute__((ext_vector_type(16))) float f32x16;

union U4  { uint4 u; bf16x8 h; };
union U4f { uint4 u; f16x8 h; };

__device__ inline ushortT f2bf(float f) {
    __hip_bfloat16 h = __float2bfloat16(f);
    return *(ushortT*)&h;
}
__device__ inline uintT packbf(float a, float b) {
    return (uintT)f2bf(a) | ((uintT)f2bf(b) << 16);
}
__device__ inline float bfround(float f) {           // round-to-bf16, widen
    return __bfloat162float(__float2bfloat16(f));
}
__device__ inline uintT pkrtz(float a, float b) {    // v_cvt_pkrtz_f16_f32
    union { fp16x2_builtin h; uintT u; } z;
    z.h = __builtin_amdgcn_cvt_pkrtz(a, b);
    return z.u;
}
__device__ inline ushortT f2h(float f) {
    _Float16 h = (_Float16)f;
    return *(ushortT*)&h;
}
// vdst.hi31 <-> vsrc.lo31 quadrant exchange (gfx950)
__device__ inline void permswap(uintT &a, uintT &b) {
    asm volatile("v_permlane32_swap_b32 %0, %1" : "+v"(a), "+v"(b));
}

// ---------------------------------------------------------------------------
// Prep: xbf[n][256] = bf16(x[n][1..256]); WT[m*256+h*32+s][dk] = W_m[h][dk+1][s];
// WoT[s][dk] = Wo[dk+1][s].
// ---------------------------------------------------------------------------
__global__ __launch_bounds__(256) void prep_kernel(
    const float* __restrict__ x,
    const float* __restrict__ Wq, const float* __restrict__ Wk,
    const float* __restrict__ Wv, const float* __restrict__ Wo,
    ushortT* __restrict__ xbf, ushortT* __restrict__ WT,
    ushortT* __restrict__ WoT)
{
    const int b = blockIdx.x, tid = threadIdx.x;
    if (b < 1024) {
        const int tok = b * 8 + (tid >> 5);
        const int c   = (tid & 31) * 8;
        const float* src = x + (size_t)tok * SD + 1 + c;
        uint4 w4;
        w4.x = packbf(src[0], src[1]);
        w4.y = packbf(src[2], src[3]);
        w4.z = packbf(src[4], src[5]);
        w4.w = packbf(src[6], src[7]);
        *(uint4*)(xbf + (size_t)tok * 256 + c) = w4;
    } else if (b < 1120) {
        const int row = (b - 1024) * 8 + (tid >> 5);
        const int dk  = (tid & 31) * 8;
        const int m = row >> 8, h = (row >> 5) & 7, s = row & 31;
        const float* Wsrc = (m == 0 ? Wq : (m == 1 ? Wk : Wv)) + (size_t)h * SD * HS + s;
        uint4 w4;
        w4.x = packbf(Wsrc[(size_t)(dk + 1) * HS], Wsrc[(size_t)(dk + 2) * HS]);
        w4.y = packbf(Wsrc[(size_t)(dk + 3) * HS], Wsrc[(size_t)(dk + 4) * HS]);
        w4.z = packbf(Wsrc[(size_t)(dk + 5) * HS], Wsrc[(size_t)(dk + 6) * HS]);
        w4.w = packbf(Wsrc[(size_t)(dk + 7) * HS], Wsrc[(size_t)(dk + 8) * HS]);
        *(uint4*)(WT + (size_t)row * 256 + dk) = w4;
    } else {
        const int s  = (b - 1120) * 8 + (tid >> 5);
        const int dk = (tid & 31) * 8;
        const float* src = Wo + (size_t)(dk + 1) * SS + s;
        uint4 w4;
        w4.x = packbf(src[0 * SS], src[1 * SS]);
        w4.y = packbf(src[2 * SS], src[3 * SS]);
        w4.z = packbf(src[4 * SS], src[5 * SS]);
        w4.w = packbf(src[6 * SS], src[7 * SS]);
        *(uint4*)(WoT + (size_t)s * 256 + dk) = w4;
    }
}

// ---------------------------------------------------------------------------
// Proj via MFMA (verified round 10). Unified q/k/v path: D[s][tok]. Grid=1024:
// block = (token-tile, mat-half); wave handles 3 of 12 mats -> 4 waves/SIMD.
// qx row (stride 48): [qs*SCL2 (32) | -u,-u,-du,1 | 0 x12]
// kx row (stride 48): [ks (32)      |  v,dv,v,M02 | 0 x12]
// vtT stored fp16 transposed [bh][d][n].
// ---------------------------------------------------------------------------
__global__ __launch_bounds__(256) void proj_mfma(
    const float* __restrict__ x, const ushortT* __restrict__ xbf,
    const ushortT* __restrict__ WT,
    const float* __restrict__ Wq, const float* __restrict__ Wk,
    const float* __restrict__ Wv,
    const float* __restrict__ bq, const float* __restrict__ bk,
    const float* __restrict__ bv,
    ushortT* __restrict__ qx, ushortT* __restrict__ kx,
    ushortT* __restrict__ vtT)
{
    const int tok0 = (blockIdx.x >> 1) * 16;
    const int mh   = (blockIdx.x & 1) * 12;
    const int w = threadIdx.x >> 6, lane = threadIdx.x & 63;
    const int g = lane >> 4, c = lane & 15;
    const int b = tok0 >> 11, n0 = tok0 & (NN - 1);

    U4 xf[8];
    const ushortT* xr = xbf + (size_t)(tok0 + c) * 256 + 8 * g;
    #pragma unroll
    for (int k = 0; k < 8; ++k) xf[k].u = *(const uint4*)(xr + 32 * k);
    const float xt1 = x[(size_t)(tok0 + c) * SD];

    for (int i = 0; i < 3; ++i) {
        const int mt = mh + w * 3 + i;
        const int m = mt >> 3, h = mt & 7;
        const ushortT* Wb = WT + (size_t)mt * 32 * 256;
        const float* Wsrc = (m == 0 ? Wq : (m == 1 ? Wk : Wv)) + (size_t)h * SD * HS;
        const float* bsrc = (m == 0 ? bq : (m == 1 ? bk : bv)) + h * HS;

        f32x4 a0 = {0.f,0.f,0.f,0.f}, a1 = {0.f,0.f,0.f,0.f};
        #pragma unroll
        for (int k = 0; k < 8; ++k) {
            U4 A0, A1;
            A0.u = *(const uint4*)(Wb + (size_t)c * 256 + 32 * k + 8 * g);
            A1.u = *(const uint4*)(Wb + (size_t)(16 + c) * 256 + 32 * k + 8 * g);
            a0 = __builtin_amdgcn_mfma_f32_16x16x32_bf16(A0.h, xf[k].h, a0, 0, 0, 0);
            a1 = __builtin_amdgcn_mfma_f32_16x16x32_bf16(A1.h, xf[k].h, a1, 0, 0, 0);
        }
        float ns = 0.f;
        #pragma unroll
        for (int r = 0; r < 4; ++r) {
            a0[r] = fmaf(Wsrc[4 * g + r], xt1, a0[r]) + bsrc[4 * g + r];
            a1[r] = fmaf(Wsrc[16 + 4 * g + r], xt1, a1[r]) + bsrc[16 + 4 * g + r];
            ns += a0[r] * a0[r] + a1[r] * a1[r];
        }
        ns += __shfl_xor(ns, 16, 64);
        ns += __shfl_xor(ns, 32, 64);           // full |space|^2 of token c
        const float tcomp = sqrtf(INV_CURV + ns); // time component

        if (m < 2) {
            const size_t tb = (size_t)(b * NH + h) * NN + n0 + c;
            ushortT* dst = (m == 0 ? qx : kx) + tb * 48;
            uint2 u0, u1;
            if (m == 0) {
                u0.x = packbf(a0[0]*SCL2, a0[1]*SCL2); u0.y = packbf(a0[2]*SCL2, a0[3]*SCL2);
                u1.x = packbf(a1[0]*SCL2, a1[1]*SCL2); u1.y = packbf(a1[2]*SCL2, a1[3]*SCL2);
            } else {
                u0.x = packbf(a0[0], a0[1]); u0.y = packbf(a0[2], a0[3]);
                u1.x = packbf(a1[0], a1[1]); u1.y = packbf(a1[2], a1[3]);
            }
            *(uint2*)(dst + 4 * g) = u0;
            *(uint2*)(dst + 16 + 4 * g) = u1;
            if (g == 2) {
                uint4 e;
                if (m == 0) {
                    const float qtS = tcomp * SCL2;
                    const float uf  = bfround(qtS);
                    const float du  = qtS - uf;
                    e.x = packbf(-uf, -uf);
                    e.y = packbf(-du, 1.0f);
                } else {
                    const float vf = bfround(tcomp);
                    const float dv = tcomp - vf;
                    e.x = packbf(tcomp, dv);
                    e.y = packbf(tcomp, M02);
                }
                e.z = 0u; e.w = 0u;
                *(uint4*)(dst + 32) = e;
            }
            if (g == 3) {
                uint4 z; z.x = 0u; z.y = 0u; z.z = 0u; z.w = 0u;
                *(uint4*)(dst + 40) = z;
            }
        } else {
            const float xn  = sqrtf(fmaxf(ns, EPSF));
            const float z   = fmaxf(tcomp / RCONST, 1.0f + 1e-7f);
            const float dd  = RCONST * logf(z + sqrtf(z * z - 1.0f));
            const float fac = dd / xn;
            const size_t vb = (size_t)(b * NH + h) * HS;
            #pragma unroll
            for (int r = 0; r < 4; ++r) {
                vtT[(vb + 4 * g + r) * NN + n0 + c]      = f2h(fac * a0[r]);
                vtT[(vb + 16 + 4 * g + r) * NN + n0 + c] = f2h(fac * a1[r]);
            }
        }
    }
}

// ---------------------------------------------------------------------------
// Kernel 2: flash attention, in-block K-split x4 + XCD swizzle (verified
// round 13). Epilogue emits bf16 cat directly + per-(token,head) sumsq hsq
// (verified round 15).
// ---------------------------------------------------------------------------
__global__ __launch_bounds__(256) void attn_mfma32s(
    const ushortT* __restrict__ qx, const ushortT* __restrict__ kx,
    const ushortT* __restrict__ vtT, ushortT* __restrict__ catbf,
    float* __restrict__ hsq)
{
    __shared__ float lacc[4][32][33];
    __shared__ float lsum[4][32];
    const int wk   = (blockIdx.x & 7) * 256 + (blockIdx.x >> 3);
    const int bh   = wk >> 6;
    const int qblk = wk & 63;
    const int wid  = threadIdx.x >> 6;
    const int lane = threadIdx.x & 63;
    const int h2 = lane >> 5;          // k-half selector
    const int cq = lane & 31;          // col index (q / key / d per fragment)
    const int qb = qblk * 32;

    const size_t bhNN = (size_t)bh * NN;
    U4 qf0, qf1, qf2;
    const ushortT* qrow = qx + (bhNN + qb + cq) * 48;
    qf0.u = *(const uint4*)(qrow + 8 * h2);
    qf1.u = *(const uint4*)(qrow + 16 + 8 * h2);
    qf2.u = *(const uint4*)(qrow + 32 + 8 * h2);

    f32x16 acc = {0.f,0.f,0.f,0.f,0.f,0.f,0.f,0.f,
                  0.f,0.f,0.f,0.f,0.f,0.f,0.f,0.f};
    float sum = 0.f;

    const ushortT* kp = kx  + bhNN * 48;
    const ushortT* vp = vtT + bhNN * HS;   // [32 d][NN], fp16

    const int tBeg = wid * 512;
    #pragma unroll 2
    for (int t = tBeg; t < tBeg + 512; t += 32) {
        const ushortT* krow = kp + (size_t)(t + cq) * 48;
        U4 k0, k1, k2;
        k0.u = *(const uint4*)(krow + 8 * h2);
        k1.u = *(const uint4*)(krow + 16 + 8 * h2);
        k2.u = *(const uint4*)(krow + 32 + 8 * h2);
        f32x16 sc = {0.f,0.f,0.f,0.f,0.f,0.f,0.f,0.f,
                     0.f,0.f,0.f,0.f,0.f,0.f,0.f,0.f};
        sc = __builtin_amdgcn_mfma_f32_32x32x16_bf16(k0.h, qf0.h, sc, 0, 0, 0);
        sc = __builtin_amdgcn_mfma_f32_32x32x16_bf16(k1.h, qf1.h, sc, 0, 0, 0);
        sc = __builtin_amdgcn_mfma_f32_32x32x16_bf16(k2.h, qf2.h, sc, 0, 0, 0);

        float p[16];
        #pragma unroll
        for (int r = 0; r < 16; ++r) {
            p[r] = __builtin_amdgcn_exp2f(sc[r]);
            sum += p[r];
        }
        uintT w0 = pkrtz(p[0],  p[1]),  w1 = pkrtz(p[2],  p[3]);
        uintT w2 = pkrtz(p[4],  p[5]),  w3 = pkrtz(p[6],  p[7]);
        uintT w4 = pkrtz(p[8],  p[9]),  w5 = pkrtz(p[10], p[11]);
        uintT w6 = pkrtz(p[12], p[13]), w7 = pkrtz(p[14], p[15]);
        permswap(w0, w2); permswap(w1, w3);   // keys 0-15 B-frag
        permswap(w4, w6); permswap(w5, w7);   // keys 16-31 B-frag
        U4f pa, pb;
        pa.u.x = w0; pa.u.y = w1; pa.u.z = w2; pa.u.w = w3;
        pb.u.x = w4; pb.u.y = w5; pb.u.z = w6; pb.u.w = w7;

        U4f v0, v1;
        v0.u = *(const uint4*)(vp + (size_t)cq * NN + t + 8 * h2);
        v1.u = *(const uint4*)(vp + (size_t)cq * NN + t + 16 + 8 * h2);
        acc = __builtin_amdgcn_mfma_f32_32x32x16_f16(v0.h, pa.h, acc, 0, 0, 0);
        acc = __builtin_amdgcn_mfma_f32_32x32x16_f16(v1.h, pb.h, acc, 0, 0, 0);
    }

    sum += __shfl_xor(sum, 32, 64);           // this wave's denominator, query cq
    if (lane < 32) lsum[wid][cq] = sum;
    #pragma unroll
    for (int r = 0; r < 16; ++r)
        lacc[wid][cq][(r & 3) + 8 * (r >> 2) + 4 * h2] = acc[r];
    __syncthreads();

    // Combine 4 key-splits; 8 threads per query, 4 dims each.
    const int qq = threadIdx.x >> 3;
    const int d0 = (threadIdx.x & 7) * 4;
    const float s   = lsum[0][qq] + lsum[1][qq] + lsum[2][qq] + lsum[3][qq];
    const float inv = 1.0f / s;
    float tv[4];
    float un2 = 0.f;
    #pragma unroll
    for (int i = 0; i < 4; ++i) {
        tv[i] = (lacc[0][qq][d0 + i] + lacc[1][qq][d0 + i]
               + lacc[2][qq][d0 + i] + lacc[3][qq][d0 + i]) * inv;
        un2 = fmaf(tv[i], tv[i], un2);
    }
    un2 += __shfl_xor(un2, 1, 64);
    un2 += __shfl_xor(un2, 2, 64);
    un2 += __shfl_xor(un2, 4, 64);            // full 32-dim sumsq of query qq
    const float un  = sqrtf(fmaxf(un2, 1e-18f));
    const float fac = RCONST * sinhf(un / RCONST) / un;

    const int b = bh >> 3, hH = bh & 7;
    const size_t tokIdx = (size_t)(b * NN + qb + qq);
    uint2 o2;
    o2.x = packbf(fac * tv[0], fac * tv[1]);
    o2.y = packbf(fac * tv[2], fac * tv[3]);
    *(uint2*)(catbf + tokIdx * SS + hH * HS + d0) = o2;
    if ((threadIdx.x & 7) == 0)
        hsq[tokIdx * NH + hH] = fac * fac * un2;   // |space_h|^2 of this head
}

// ---------------------------------------------------------------------------
// Kernel 3: output Lorentz FC via MFMA (verified round 15 form).
// ---------------------------------------------------------------------------
__global__ __launch_bounds__(256) void out_mfma(
    const ushortT* __restrict__ catbf, const ushortT* __restrict__ WoT,
    const float* __restrict__ Wo, const float* __restrict__ bo,
    const float* __restrict__ hsq, float* __restrict__ out)
{
    __shared__ float ylds[16][SS + 1];
    __shared__ float redt[16][4];
    const int tok0 = blockIdx.x * 16;
    const int w = threadIdx.x >> 6, lane = threadIdx.x & 63;
    const int g = lane >> 4, c = lane & 15;

    U4 bf[8];
    const ushortT* cr = catbf + (size_t)(tok0 + c) * SS + 8 * g;
    #pragma unroll
    for (int k = 0; k < 8; ++k) bf[k].u = *(const uint4*)(cr + 32 * k);

    const float4 h0 = *(const float4*)(hsq + (size_t)(tok0 + c) * NH);
    const float4 h1 = *(const float4*)(hsq + (size_t)(tok0 + c) * NH + 4);
    const float timec = sqrtf(INV_CURV + h0.x + h0.y + h0.z + h0.w
                                        + h1.x + h1.y + h1.z + h1.w);

    float ysq = 0.f;
    #pragma unroll
    for (int t4 = 0; t4 < 4; ++t4) {
        const int t = 4 * w + t4;
        f32x4 a = {0.f, 0.f, 0.f, 0.f};
        #pragma unroll
        for (int k = 0; k < 8; ++k) {
            U4 A;
            A.u = *(const uint4*)(WoT + (size_t)(16 * t + c) * 256 + 32 * k + 8 * g);
            a = __builtin_amdgcn_mfma_f32_16x16x32_bf16(A.h, bf[k].h, a, 0, 0, 0);
        }
        #pragma unroll
        for (int r = 0; r < 4; ++r) {
            const int s = 16 * t + 4 * g + r;
            const float y = a[r] + fmaf(Wo[s], timec, bo[s]);  // Wo row 0 = time row
            ylds[c][s] = y;
            ysq = fmaf(y, y, ysq);
        }
    }
    ysq += __shfl_xor(ysq, 16, 64);
    ysq += __shfl_xor(ysq, 32, 64);   // per (w,c): Sigma over this wave's 64 s
    if (lane < 16) redt[c][w] = ysq;
    __syncthreads();

    #pragma unroll
    for (int j = 0; j < 16; ++j)
        out[(size_t)(tok0 + j) * SD + 1 + threadIdx.x] = ylds[j][threadIdx.x];
    if (threadIdx.x < 16) {
        const int j = threadIdx.x;
        const float ys = redt[j][0] + redt[j][1] + redt[j][2] + redt[j][3];
        out[(size_t)(tok0 + j) * SD] = sqrtf(INV_CURV + ys);
    }
}

// ---------------------------------------------------------------------------
extern "C" void kernel_launch(void* const* d_in, const int* in_sizes, int n_in,
                              void* d_out, int out_size, void* d_ws, size_t ws_size,
                              hipStream_t stream)
{
    const float* x  = (const float*)d_in[0];
    const float* Wq = (const float*)d_in[1];
    const float* bq = (const float*)d_in[2];
    const float* Wk = (const float*)d_in[3];
    const float* bk = (const float*)d_in[4];
    const float* Wv = (const float*)d_in[5];
    const float* bv = (const float*)d_in[6];
    const float* Wo = (const float*)d_in[7];
    const float* bo = (const float*)d_in[8];
    float* out = (float*)d_out;

    char* w = (char*)d_ws;
    ushortT* xbf   = (ushortT*)(w);                         // 4 MB
    ushortT* qx    = (ushortT*)(w + (size_t)4194304);       // 6 MB (48-dim rows)
    ushortT* kx    = (ushortT*)(w + (size_t)10485760);      // 6 MB
    ushortT* vtT   = (ushortT*)(w + (size_t)16777216);      // 4 MB (fp16)
    ushortT* catbf = (ushortT*)(w + (size_t)20971520);      // 4 MB (bf16)
    ushortT* WT    = (ushortT*)(w + (size_t)25165824);      // 384 KB
    ushortT* WoT   = (ushortT*)(w + (size_t)25559040);      // 128 KB
    float*   hsq   = (float*)  (w + (size_t)25690112);      // 256 KB

    prep_kernel<<<1152, 256, 0, stream>>>(x, Wq, Wk, Wv, Wo, xbf, WT, WoT);
    proj_mfma<<<BB * NN / 16 * 2, 256, 0, stream>>>(x, xbf, WT, Wq, Wk, Wv,
                                                    bq, bk, bv, qx, kx, vtT);
    attn_mfma32s<<<2048, 256, 0, stream>>>(qx, kx, vtT, catbf, hsq);
    out_mfma<<<BB * NN / 16, 256, 0, stream>>>(catbf, WoT, Wo, bo, hsq, out);
}